// Round 9
// baseline (113.827 us; speedup 1.0000x reference)
//
#include <hip/hip_runtime.h>
#include <hip/hip_fp16.h>

typedef _Float16 half8 __attribute__((ext_vector_type(8)));
typedef _Float16 half4v __attribute__((ext_vector_type(4)));
typedef float    floatx4 __attribute__((ext_vector_type(4)));

#define MFMA16(a, b, c) __builtin_amdgcn_mfma_f32_16x16x32_f16((a), (b), (c), 0, 0, 0)

constexpr int T_ = 2048;
constexpr int D_ = 1024;
constexpr int NB = 4;
constexpr int NTILE = 136;             // lower-tri 128x128 tiles per batch
constexpr size_t TILE_ELEMS = 16384;   // 128*128

__device__ __forceinline__ half8 cvt8(floatx4 a, floatx4 b) {
  half8 h;
  h[0] = (_Float16)a[0]; h[1] = (_Float16)a[1]; h[2] = (_Float16)a[2]; h[3] = (_Float16)a[3];
  h[4] = (_Float16)b[0]; h[5] = (_Float16)b[1]; h[6] = (_Float16)b[2]; h[7] = (_Float16)b[3];
  return h;
}

__device__ __forceinline__ void gl16(const void* g, void* l) {
  __builtin_amdgcn_global_load_lds(
      (const __attribute__((address_space(1))) void*)g,
      (__attribute__((address_space(3))) void*)l, 16, 0, 0);
}

__device__ __forceinline__ void STEP_SYNC() {
  asm volatile("s_waitcnt vmcnt(0)" ::: "memory");
  __builtin_amdgcn_s_barrier();
  __builtin_amdgcn_sched_barrier(0);
}

// ---- prep 1: Q f32 -> f16 straight cast (linear) ----
__global__ __launch_bounds__(256) void cast_q(const float* __restrict__ Q,
                                              _Float16* __restrict__ Qh) {
  const size_t i = ((size_t)blockIdx.x * 256 + threadIdx.x) * 8;
  *(half8*)(Qh + i) = cvt8(*(const floatx4*)(Q + i), *(const floatx4*)(Q + i + 4));
}

// ---- prep 2: VhT[b][d][t] f16 plain transpose ----
__global__ __launch_bounds__(256) void build_vt(const float* __restrict__ V,
                                                _Float16* __restrict__ VhT) {
  __shared__ _Float16 tile[64][65];
  const int bid = blockIdx.x;
  const int b = bid & 3, tt = (bid >> 2) & 31, dd = bid >> 7;
  const float* Vb = V + ((size_t)b * T_ + tt * 64) * D_ + dd * 64;
#pragma unroll
  for (int k = 0; k < 16; ++k) {
    const int e = k * 256 + threadIdx.x, r = e >> 6, c = e & 63;
    tile[r][c] = (_Float16)Vb[(size_t)r * D_ + c];
  }
  __syncthreads();
#pragma unroll
  for (int k = 0; k < 16; ++k) {
    const int e = k * 256 + threadIdx.x, dr = e >> 6, tc = e & 63;
    VhT[((size_t)b * D_ + dd * 64 + dr) * T_ + tt * 64 + tc] = tile[tc][dr];
  }
}

// ---- S-GEMM: S = Q*V^T (NT), 128^2 tile, BK=32, 2-phase dbuf gload_lds ----
__global__ __launch_bounds__(256, 3) void sgemm(const _Float16* __restrict__ Qh,
                                                const float* __restrict__ V,
                                                float* __restrict__ Sp) {
  __shared__ __align__(16) char lds[49152];   // [2][ A 8K f16 | B 16K f32 ]
  const int tid = threadIdx.x;
  const int w = tid >> 6, l = tid & 63, l15 = l & 15, hi = l >> 4;
  const int wr = (w >> 1) * 64, wc = (w & 1) * 64;
  const int l2 = l >> 2, l3 = l >> 3;

  const int b = (int)(blockIdx.x & 3);
  int rem = (int)(blockIdx.x >> 2), j = 0;      // j-major (B-panel L2 reuse)
  while (rem >= 16 - j) { rem -= 16 - j; ++j; }
  const int i = j + rem;

  const _Float16* Qb = Qh + ((size_t)(b * T_ + i * 128)) * D_;
  const float*    Vb = V  + ((size_t)(b * T_ + j * 128)) * D_;

  auto STAGE = [&](const int s, const int buf) {
    char* Ad = lds + buf * 24576 + w * 2048;
    char* Bd = lds + buf * 24576 + 8192 + w * 4096;
#pragma unroll
    for (int q = 0; q < 2; ++q) {               // A: 128 rows x 32 k f16
      const int ar = w * 32 + q * 16 + l2;
      const int sw = (ar + (ar >> 2)) & 3;
      gl16(Qb + (size_t)ar * D_ + s * 32 + (((l & 3) ^ sw) << 3), Ad + q * 1024);
    }
#pragma unroll
    for (int q = 0; q < 4; ++q) {               // B: 128 rows x 32 k f32
      const int br = w * 32 + q * 8 + l3;
      gl16(Vb + (size_t)br * D_ + s * 32 + (((l & 7) ^ (br & 7)) << 2), Bd + q * 1024);
    }
  };

  floatx4 acc[4][4];
#pragma unroll
  for (int mi = 0; mi < 4; ++mi)
#pragma unroll
    for (int ni = 0; ni < 4; ++ni) acc[mi][ni] = (floatx4){0.f, 0.f, 0.f, 0.f};

  STAGE(0, 0);
  STEP_SYNC();
  for (int s = 0; s < 32; ++s) {
    const int buf = s & 1;
    if (s + 1 < 32) STAGE(s + 1, buf ^ 1);      // in flight across COMP
    const char* Ab = lds + buf * 24576;
    const char* Bb = lds + buf * 24576 + 8192;
    half8 af[4], bb[4];
#pragma unroll
    for (int mi = 0; mi < 4; ++mi) {
      const int row = wr + mi * 16 + l15;
      const int sw = (row + (row >> 2)) & 3;
      af[mi] = *(const half8*)(Ab + row * 64 + ((hi ^ sw) << 4));
    }
#pragma unroll
    for (int ni = 0; ni < 4; ++ni) {
      const int row = wc + ni * 16 + l15;
      const int p0 = (hi << 1) ^ (row & 7);
      const floatx4 f0 = *(const floatx4*)(Bb + row * 128 + (p0 << 4));
      const floatx4 f1 = *(const floatx4*)(Bb + row * 128 + ((p0 ^ 1) << 4));
      bb[ni] = cvt8(f0, f1);
    }
#pragma unroll
    for (int mi = 0; mi < 4; ++mi)
#pragma unroll
      for (int ni = 0; ni < 4; ++ni)
        acc[mi][ni] = MFMA16(af[mi], bb[ni], acc[mi][ni]);
    STEP_SYNC();                                // waits STAGE(s+1); next overwrite gated
  }

  float* tp = Sp + (size_t)(b * NTILE + ((i * (i + 1)) >> 1) + j) * TILE_ELEMS;
#pragma unroll
  for (int mi = 0; mi < 4; ++mi)
#pragma unroll
    for (int r = 0; r < 4; ++r) {
      const int row = wr + mi * 16 + 4 * hi + r;
#pragma unroll
      for (int ni = 0; ni < 4; ++ni)
        tp[row * 128 + wc + ni * 16 + l15] = acc[mi][ni][r];
    }
}

// ---- softmax: half-wave per row, float4; P f16 in-place (row slot 512B) ----
__global__ __launch_bounds__(256) void smax(float* __restrict__ Sp,
                                            float* __restrict__ lrow) {
  const int b = (int)(blockIdx.x & 3), t = (int)(blockIdx.x >> 2);
  const int wv = threadIdx.x >> 6, l = threadIdx.x & 63;
  const int l32 = l & 31;
  const int row = 2040 - t * 8 + wv * 2 + (l >> 5);   // LPT: long rows first
  const int i = row >> 7, r = row & 127;
  char* tb0 = (char*)(Sp + (size_t)(b * NTILE + ((i * (i + 1)) >> 1)) * TILE_ELEMS);

  float mx = -1e30f;
  for (int j = 0; j <= i; ++j) {
    const floatx4 v = *(const floatx4*)(tb0 + (size_t)j * 65536 + r * 512 + l32 * 16);
    const int col0 = j * 128 + l32 * 4;
#pragma unroll
    for (int e = 0; e < 4; ++e)
      if (col0 + e <= row) mx = fmaxf(mx, v[e]);
  }
#pragma unroll
  for (int off = 1; off < 32; off <<= 1) mx = fmaxf(mx, __shfl_xor(mx, off));

  float sum = 0.f;
  for (int j = 0; j <= i; ++j) {
    char* tbj = tb0 + (size_t)j * 65536;
    const floatx4 v = *(const floatx4*)(tbj + r * 512 + l32 * 16);
    const int col0 = j * 128 + l32 * 4;
    half4v hv;
#pragma unroll
    for (int e = 0; e < 4; ++e) {
      const float p = (col0 + e <= row) ? __expf(v[e] - mx) : 0.f;
      sum += p;
      hv[e] = (_Float16)p;
    }
    *(half4v*)(tbj + r * 512 + l32 * 8) = hv;   // own row slot only
  }
#pragma unroll
  for (int off = 1; off < 32; off <<= 1) sum += __shfl_xor(sum, off);
  if (l32 == 0) lrow[b * 2048 + row] = sum;
}

// ---- PV: O = P*V (via VhT), 128^2 tile, BK=32, 2-phase dbuf, LPT pairs ----
__global__ __launch_bounds__(256, 3) void pv(const float* __restrict__ Sp,
                                             const _Float16* __restrict__ VhT,
                                             const float* __restrict__ lrow,
                                             float* __restrict__ O) {
  __shared__ __align__(16) char lds[32768];   // [2][ A 8K | B 8K ] f16
  __shared__ float Lsh[128];
  const int tid = threadIdx.x;
  const int w = tid >> 6, l = tid & 63, l15 = l & 15, hi = l >> 4;
  const int wr = (w >> 1) * 64, wc = (w & 1) * 64;
  const int l2 = l >> 2;

  const int b = (int)(blockIdx.x & 3), t = (int)(blockIdx.x >> 2);
  const int r_ = t >> 3;
  const int i = (r_ < 8) ? (15 - r_) : (r_ - 8);   // co-resident pair balance
  const int nc = t & 7;
  const int ns = (i + 1) * 4;

  const char* Pbase = (const char*)(Sp + (size_t)(b * NTILE + ((i * (i + 1)) >> 1)) * TILE_ELEMS);
  const _Float16* Vt = VhT + ((size_t)(b * D_ + nc * 128)) * T_;
  if (tid < 128) Lsh[tid] = lrow[b * 2048 + i * 128 + tid];

  auto STAGE = [&](const int s, const int buf) {
    char* Ad = lds + buf * 16384 + w * 2048;
    char* Bd = lds + buf * 16384 + 8192 + w * 2048;
#pragma unroll
    for (int q = 0; q < 2; ++q) {
      const int ar = w * 32 + q * 16 + l2;
      const int sw = (ar + (ar >> 2)) & 3;
      gl16(Pbase + (size_t)(s >> 2) * 65536 + ar * 512 + (s & 3) * 64 +
               (((l & 3) ^ sw) << 4),
           Ad + q * 1024);
      gl16(Vt + (size_t)ar * T_ + s * 32 + (((l & 3) ^ sw) << 3), Bd + q * 1024);
    }
  };

  floatx4 acc[4][4];
#pragma unroll
  for (int mi = 0; mi < 4; ++mi)
#pragma unroll
    for (int ni = 0; ni < 4; ++ni) acc[mi][ni] = (floatx4){0.f, 0.f, 0.f, 0.f};

  STAGE(0, 0);
  STEP_SYNC();
  for (int s = 0; s < ns; ++s) {
    const int buf = s & 1;
    if (s + 1 < ns) STAGE(s + 1, buf ^ 1);
    const char* Ab = lds + buf * 16384;
    const char* Bb = lds + buf * 16384 + 8192;
    half8 af[4], bb[4];
#pragma unroll
    for (int mi = 0; mi < 4; ++mi) {
      const int row = wr + mi * 16 + l15;
      const int sw = (row + (row >> 2)) & 3;
      af[mi] = *(const half8*)(Ab + row * 64 + ((hi ^ sw) << 4));
    }
#pragma unroll
    for (int ni = 0; ni < 4; ++ni) {
      const int row = wc + ni * 16 + l15;
      const int sw = (row + (row >> 2)) & 3;
      bb[ni] = *(const half8*)(Bb + row * 64 + ((hi ^ sw) << 4));
    }
#pragma unroll
    for (int mi = 0; mi < 4; ++mi)
#pragma unroll
      for (int ni = 0; ni < 4; ++ni)
        acc[mi][ni] = MFMA16(af[mi], bb[ni], acc[mi][ni]);
    STEP_SYNC();
  }

  float* Ob = O + ((size_t)b * T_ + i * 128) * D_ + nc * 128;
#pragma unroll
  for (int mi = 0; mi < 4; ++mi)
#pragma unroll
    for (int r = 0; r < 4; ++r) {
      const int rl = wr + mi * 16 + 4 * hi + r;
      const float inv = 1.0f / Lsh[rl];
#pragma unroll
      for (int ni = 0; ni < 4; ++ni)
        Ob[(size_t)rl * D_ + wc + ni * 16 + l15] = acc[mi][ni][r] * inv;
    }
}

// ---- fallback (ws too small — slow but correct) ----
__global__ __launch_bounds__(256) void attn_fb(const float* __restrict__ Q,
                                               const float* __restrict__ V,
                                               float* __restrict__ O) {
  __shared__ float sc[2048];
  __shared__ float red[4];
  const int b = (int)(blockIdx.x >> 11), m = (int)(blockIdx.x & 2047);
  const int tid = threadIdx.x;
  const float* Qr = Q + ((size_t)b * T_ + m) * D_;
  for (int kv = tid; kv <= m; kv += 256) {
    const float* Vr = V + ((size_t)b * T_ + kv) * D_;
    float s = 0.f;
    for (int d = 0; d < D_; d += 4) {
      floatx4 q4 = *(const floatx4*)(Qr + d), v4 = *(const floatx4*)(Vr + d);
      s += q4[0] * v4[0] + q4[1] * v4[1] + q4[2] * v4[2] + q4[3] * v4[3];
    }
    sc[kv] = s;
  }
  __syncthreads();
  float mx = -1e30f;
  for (int kv = tid; kv <= m; kv += 256) mx = fmaxf(mx, sc[kv]);
#pragma unroll
  for (int off = 1; off < 64; off <<= 1) mx = fmaxf(mx, __shfl_xor(mx, off));
  if ((tid & 63) == 0) red[tid >> 6] = mx;
  __syncthreads();
  mx = fmaxf(fmaxf(red[0], red[1]), fmaxf(red[2], red[3]));
  __syncthreads();
  float sum = 0.f;
  for (int kv = tid; kv <= m; kv += 256) { float p = __expf(sc[kv] - mx); sc[kv] = p; sum += p; }
#pragma unroll
  for (int off = 1; off < 64; off <<= 1) sum += __shfl_xor(sum, off);
  __syncthreads();
  if ((tid & 63) == 0) red[tid >> 6] = sum;
  __syncthreads();
  const float inv = 1.0f / (red[0] + red[1] + red[2] + red[3]);
  float* Or = O + ((size_t)b * T_ + m) * D_;
  const int d = tid * 4;
  floatx4 o = {0.f, 0.f, 0.f, 0.f};
  for (int kv = 0; kv <= m; ++kv) {
    const float p = sc[kv];
    const floatx4 v4 = *(const floatx4*)(V + ((size_t)b * T_ + kv) * D_ + d);
    o[0] += p * v4[0]; o[1] += p * v4[1]; o[2] += p * v4[2]; o[3] += p * v4[3];
  }
  o[0] *= inv; o[1] *= inv; o[2] *= inv; o[3] *= inv;
  *(floatx4*)(Or + d) = o;
}

extern "C" void kernel_launch(void* const* d_in, const int* in_sizes, int n_in,
                              void* d_out, int out_size, void* d_ws, size_t ws_size,
                              hipStream_t stream) {
  const float* q = (const float*)d_in[0];
  const float* v = (const float*)d_in[1];
  float* out = (float*)d_out;

  const size_t OFF_S = 16777216;                                    // Qh/VhT slot (reused)
  const size_t OFF_L = OFF_S + (size_t)NB * NTILE * TILE_ELEMS * 4; // 52,428,800
  const size_t NEED = OFF_L + (size_t)NB * 2048 * 4;                // ~52.5 MB

  if (ws_size >= NEED) {
    _Float16* fh = (_Float16*)d_ws;                 // Qh, later VhT
    float* Sp = (float*)((char*)d_ws + OFF_S);
    float* lr = (float*)((char*)d_ws + OFF_L);
    cast_q<<<dim3(4096), dim3(256), 0, stream>>>(q, fh);
    sgemm<<<dim3(NB * NTILE), dim3(256), 0, stream>>>(fh, v, Sp);
    smax<<<dim3(1024), dim3(256), 0, stream>>>(Sp, lr);
    build_vt<<<dim3(2048), dim3(256), 0, stream>>>(v, fh);   // Qh dead -> VhT
    pv<<<dim3(512), dim3(256), 0, stream>>>(Sp, fh, lr, out);
  } else {
    attn_fb<<<dim3(NB * T_), dim3(256), 0, stream>>>(q, v, out);
  }
}